// Round 8
// baseline (244.200 us; speedup 1.0000x reference)
//
#include <hip/hip_runtime.h>
#include <hip/hip_bf16.h>

// Problem constants: B=256, N=128, EB=5, NA=64, DIM=512, NIT=3
// out = [logit (256 f32), graph_repr (256*512 f32)]

typedef __bf16 bf16;
typedef __bf16 bf16x4 __attribute__((ext_vector_type(4)));
typedef __bf16 bf16x8 __attribute__((ext_vector_type(8)));
typedef float floatx4 __attribute__((ext_vector_type(4)));

// LDS pool = 160 KB:
//   [0, 131072): 16 wave-private 8 KB regions, time-multiplexed:
//     as HT: h^T rows d = w*32..w*32+31 live in region w (row stride 128 n,
//            16B-chunk XOR swizzle: phys chunk = c ^ (d&15))
//     as T : region w holds t[all 128 n][d = w*32..+32] as [4 dq][128 n][8 d]
//            elem = w*4096 + dq*1024 + n*8 + (d&7)
//   [131072, 163840): AhatP = packed Ahat B-frags (32 KB), written directly by the
//     prologue. frag (ntG 0..7, kk 0..3), chunk swizzle phys = mq*16 + (l16 ^ 2*mq).
//     (dead after it=2 phase-T; lpF[512] overlays here for the epilogue)
//
// Ownership invariant: wave w's phase-T reads ONLY region w (+AhatP) and writes
// ONLY region w; h'-write writes ONLY region w; embed writes ONLY region w.
// => no barrier h'-write -> phase-T -> t-write -> OWN-dc phase-W step.
// Phase-W staggered: wave w consumes regions in order w, w+1, ..., w+15; the
// dc=w step runs BEFORE B2 (self-owned data), absorbing barrier skew.

// ---------------------------------------------------------------- pack W into MFMA B-fragment order
// src f32 [K][512] -> dst bf16: dst[((td*(K/32)+tk)*64 + lane)*8 + j]
//   = src[tk*32 + (lane>>4)*8 + j][td*16 + (lane&15)]
// element address = td*(K/32)*512 + tk*512 + lane*8 + j   (per-td stride 8192 when K=512)
// grid: (td=32, z=4): z<3 -> W_layers[z] (K=512); z==3 -> W_embed (K=64)
__global__ __launch_bounds__(256) void k_pack(const float* __restrict__ We,
                                              const float* __restrict__ Wl,
                                              bf16* __restrict__ PWe,
                                              bf16* __restrict__ PWl) {
    __shared__ float S[512][17];
    int z = blockIdx.y, td = blockIdx.x;
    const float* src; bf16* dst; int K;
    if (z < 3) { src = Wl + (size_t)z * 262144; dst = PWl + (size_t)z * 262144; K = 512; }
    else       { src = We;                      dst = PWe;                      K = 64; }
    int tid = threadIdx.x;
    int x = tid & 15, y = tid >> 4;
    for (int kb = 0; kb < K; kb += 16) {
        int k = kb + y;
        S[k][x] = src[(size_t)k * 512 + td * 16 + x];
    }
    __syncthreads();
    int lane = tid & 63, w = tid >> 6, q = lane >> 4, l16 = lane & 15;
    int KT = K >> 5;
    for (int tk = w; tk < KT; tk += 4) {
        bf16x8 v;
#pragma unroll
        for (int j = 0; j < 8; j++) v[j] = (bf16)S[tk * 32 + q * 8 + j][l16];
        *(bf16x8*)&dst[(size_t)((td * KT + tk) * 64 + lane) * 8] = v;
    }
}

// ---------------------------------------------------------------- fused WLS forward
// 1024 threads (16 waves, 4/SIMD -> unified reg cap 128/wave). One block per batch.
__global__ __launch_bounds__(1024, 4) void k_mega(
    const float* __restrict__ adj,     // [256][128][128][5] f32
    const float* __restrict__ nodef,   // [256][128][64] f32
    const bf16* __restrict__ PWe,      // packed W_embed frags
    const float* __restrict__ b_embed, // [512]
    const bf16* __restrict__ PWl,      // packed W_layers frags [3][...]
    const float* __restrict__ b_layers,// [3][512]
    const float* __restrict__ W_out,   // [512]
    const float* __restrict__ b_out,   // [1]
    float* __restrict__ out)           // [256 logit][256*512 graph_repr]
{
    __shared__ __align__(16) char pool[163840];   // full 160 KB
    bf16* HT = (bf16*)pool;
    bf16* AhatP = (bf16*)(pool + 131072);

    const int b = blockIdx.x;
    const int tid = threadIdx.x;
    const int lane = tid & 63, wid = tid >> 6;     // 16 waves
    const int q = lane >> 4, l16 = lane & 15;

    // ---------------- prologue: Ahat = sum_e adj[...,1:] + I, scattered into AhatP frags
    {
        const float4* srcb = (const float4*)(adj + (size_t)b * 81920);
#pragma unroll
        for (int p = 0; p < 4; p++) {
            int t = p * 1024 + tid;                // 4-element group id, 0..4095
            const float4* ptr = srcb + (size_t)t * 5;
            float4 v0 = ptr[0], v1 = ptr[1], v2 = ptr[2], v3 = ptr[3], v4 = ptr[4];
            float s0 = v0.y + v0.z + v0.w + v1.x;
            float s1 = v1.z + v1.w + v2.x + v2.y;
            float s2 = v2.w + v3.x + v3.y + v3.z;
            float s3 = v4.x + v4.y + v4.z + v4.w;
            int n = t >> 5, m0 = (t & 31) * 4;
            bf16x4 o;
            o[0] = (bf16)(s0 + ((n == m0 + 0) ? 1.f : 0.f));
            o[1] = (bf16)(s1 + ((n == m0 + 1) ? 1.f : 0.f));
            o[2] = (bf16)(s2 + ((n == m0 + 2) ? 1.f : 0.f));
            o[3] = (bf16)(s3 + ((n == m0 + 3) ? 1.f : 0.f));
            int ntG = n >> 4, l16n = n & 15;
            int kk = m0 >> 5, mq = (m0 & 31) >> 3, half = (m0 >> 2) & 1;
            int cphys = mq * 16 + (l16n ^ (mq * 2));
            *(bf16x4*)&AhatP[(size_t)(((ntG * 4 + kk) * 64 + cphys) * 8 + half * 4)] = o;
        }
    }
    // NO barrier: embed touches only HT-own-rows/global; AhatP first read after B1.

    // ---------------- embed: HT rows wid*32..+32 = (node @ W_embed + b)^T, self-owned
    {
        const float* Ab = nodef + (size_t)b * 8192;
        floatx4 accE[8][2] = {};
#pragma unroll
        for (int kk = 0; kk < 2; kk++) {
            bf16x8 bfr[2];
#pragma unroll
            for (int nt = 0; nt < 2; nt++)
                bfr[nt] = *(const bf16x8*)&PWe[(size_t)(((wid * 2 + nt) * 2 + kk) * 64 + lane) * 8];
#pragma unroll
            for (int half = 0; half < 2; half++) {
                bf16x8 af[4];
#pragma unroll
                for (int mt = 0; mt < 4; mt++) {
                    const float* srcp = Ab + (size_t)((half * 4 + mt) * 16 + l16) * 64 + kk * 32 + q * 8;
                    float4 x = *(const float4*)srcp;
                    float4 y = *(const float4*)(srcp + 4);
                    bf16x8 v;
                    v[0] = (bf16)x.x; v[1] = (bf16)x.y; v[2] = (bf16)x.z; v[3] = (bf16)x.w;
                    v[4] = (bf16)y.x; v[5] = (bf16)y.y; v[6] = (bf16)y.z; v[7] = (bf16)y.w;
                    af[mt] = v;
                }
#pragma unroll
                for (int mt = 0; mt < 4; mt++)
#pragma unroll
                    for (int nt = 0; nt < 2; nt++)
                        accE[half * 4 + mt][nt] = __builtin_amdgcn_mfma_f32_16x16x32_bf16(af[mt], bfr[nt], accE[half * 4 + mt][nt], 0, 0, 0);
            }
        }
#pragma unroll
        for (int nt = 0; nt < 2; nt++) {
            int d = wid * 32 + nt * 16 + l16;
            float bv = b_embed[d];
#pragma unroll
            for (int mt = 0; mt < 8; mt++) {
                int c = mt * 2 + (q >> 1);                 // 16B chunk of n
                int off = ((c ^ (d & 15)) << 3) + (q & 1) * 4;
                bf16x4 pk;
#pragma unroll
                for (int r = 0; r < 4; r++) pk[r] = (bf16)(accE[mt][nt][r] + bv);
                *(bf16x4*)&HT[d * 128 + off] = pk;
            }
        }
    }
    __syncthreads();   // B1: AhatP ready (HT rows are self-owned, no sync needed for them)

    const int pc = lane ^ ((lane >> 4) * 2);       // AhatP phys chunk for this lane

    // ---------------- 3 WLS iterations (2 barriers each)
    for (int it = 0; it < 3; it++) {
        const bf16* WT = PWl + (size_t)it * 262144;
        const float* bl = b_layers + it * 512;

        // per-wave W frag base pointers: frag(td, dc) at td*8192 + dc*512 + lane*8
        const bf16* Wb0 = WT + (size_t)(wid * 2 + 0) * 8192 + lane * 8;
        const bf16* Wb1 = WT + (size_t)(wid * 2 + 1) * 8192 + lane * 8;

        // W-frag prefetch for stagger steps i=0 (dc=wid) and i=1: lands during phase-T
        bf16x8 w00 = *(const bf16x8*)(Wb0 + wid * 512);
        bf16x8 w01 = *(const bf16x8*)(Wb1 + wid * 512);
        bf16x8 w10 = *(const bf16x8*)(Wb0 + ((wid + 1) & 15) * 512);
        bf16x8 w11 = *(const bf16x8*)(Wb1 + ((wid + 1) & 15) * 512);

        // ----- phase T: at[dt][nt] = t tile [32 d x 128 n], fully wave-private, no barriers
        floatx4 at[2][8] = {};
#pragma unroll
        for (int kk = 0; kk < 4; kk++) {
            bf16x8 afr[2];
#pragma unroll
            for (int dt = 0; dt < 2; dt++) {
                int drow = wid * 32 + dt * 16 + l16;
                int off = ((4 * kk + q) ^ (drow & 15)) << 3;
                afr[dt] = *(const bf16x8*)&HT[drow * 128 + off];
            }
#pragma unroll
            for (int g = 0; g < 2; g++) {
                bf16x8 bfr[4];
#pragma unroll
                for (int nt = 0; nt < 4; nt++)
                    bfr[nt] = *(const bf16x8*)&AhatP[(size_t)(((g * 4 + nt) * 4 + kk) * 64 + pc) * 8];
                __builtin_amdgcn_s_setprio(1);
#pragma unroll
                for (int nt = 0; nt < 4; nt++)
#pragma unroll
                    for (int dt = 0; dt < 2; dt++)
                        at[dt][g * 4 + nt] = __builtin_amdgcn_mfma_f32_16x16x32_bf16(afr[dt], bfr[nt], at[dt][g * 4 + nt], 0, 0, 0);
                __builtin_amdgcn_s_setprio(0);
            }
        }
        {
            // write t into own region w: elem = wid*4096 + dq*1024 + n*8 + (d&7)
            // C frag: col n = l16 (tile nt), row d_local = dt*16 + q*4 + r
            bf16* Treg = HT + wid * 4096;
#pragma unroll
            for (int dt = 0; dt < 2; dt++)
#pragma unroll
                for (int nt = 0; nt < 8; nt++) {
                    int n = nt * 16 + l16;
                    bf16x4 pk;
#pragma unroll
                    for (int r = 0; r < 4; r++) pk[r] = (bf16)at[dt][nt][r];
                    *(bf16x4*)&Treg[(dt * 2 + (q >> 1)) * 1024 + n * 8 + (q & 1) * 4] = pk;
                }
        }

        // ----- phase W: acc = t @ W[it], staggered: dc = wid, wid+1, ..., wid+15
        floatx4 acc[8][2] = {};   // [mt: n-tile][nt: d'-tile]

        // peel i=0: dc = wid = OWN region, just written by this wave -> legal pre-barrier
        {
            int dcn = (wid + 2) & 15;
            bf16x8 n0 = *(const bf16x8*)(Wb0 + dcn * 512);
            bf16x8 n1 = *(const bf16x8*)(Wb1 + dcn * 512);
            const bf16* Tdc = HT + wid * 4096 + q * 1024 + l16 * 8;
            bf16x8 afa[4];
#pragma unroll
            for (int mt = 0; mt < 4; mt++)
                afa[mt] = *(const bf16x8*)&Tdc[mt * 128];
            __builtin_amdgcn_s_setprio(1);
#pragma unroll
            for (int mt = 0; mt < 4; mt++)
                acc[mt][0] = __builtin_amdgcn_mfma_f32_16x16x32_bf16(afa[mt], w00, acc[mt][0], 0, 0, 0);
#pragma unroll
            for (int mt = 0; mt < 4; mt++)
                acc[mt][1] = __builtin_amdgcn_mfma_f32_16x16x32_bf16(afa[mt], w01, acc[mt][1], 0, 0, 0);
            __builtin_amdgcn_s_setprio(0);
            bf16x8 afb[4];
#pragma unroll
            for (int mt = 0; mt < 4; mt++)
                afb[mt] = *(const bf16x8*)&Tdc[(mt + 4) * 128];
            __builtin_amdgcn_s_setprio(1);
#pragma unroll
            for (int mt = 0; mt < 4; mt++)
                acc[mt + 4][0] = __builtin_amdgcn_mfma_f32_16x16x32_bf16(afb[mt], w00, acc[mt + 4][0], 0, 0, 0);
#pragma unroll
            for (int mt = 0; mt < 4; mt++)
                acc[mt + 4][1] = __builtin_amdgcn_mfma_f32_16x16x32_bf16(afb[mt], w01, acc[mt + 4][1], 0, 0, 0);
            __builtin_amdgcn_s_setprio(0);
            w00 = w10; w01 = w11; w10 = n0; w11 = n1;
        }
        __syncthreads();   // B2: all t regions complete

        for (int i = 1; i < 16; i++) {
            int dc = (wid + i) & 15;
            int dcn = (wid + i + 2) & 15;   // depth-2 prefetch (wraps harmlessly at tail)
            bf16x8 n0 = *(const bf16x8*)(Wb0 + dcn * 512);
            bf16x8 n1 = *(const bf16x8*)(Wb1 + dcn * 512);
            const bf16* Tdc = HT + dc * 4096 + q * 1024 + l16 * 8;   // region dc, k-quad q
            bf16x8 afa[4];
#pragma unroll
            for (int mt = 0; mt < 4; mt++)
                afa[mt] = *(const bf16x8*)&Tdc[mt * 128];
            __builtin_amdgcn_s_setprio(1);
#pragma unroll
            for (int mt = 0; mt < 4; mt++)
                acc[mt][0] = __builtin_amdgcn_mfma_f32_16x16x32_bf16(afa[mt], w00, acc[mt][0], 0, 0, 0);
#pragma unroll
            for (int mt = 0; mt < 4; mt++)
                acc[mt][1] = __builtin_amdgcn_mfma_f32_16x16x32_bf16(afa[mt], w01, acc[mt][1], 0, 0, 0);
            __builtin_amdgcn_s_setprio(0);
            bf16x8 afb[4];
#pragma unroll
            for (int mt = 0; mt < 4; mt++)
                afb[mt] = *(const bf16x8*)&Tdc[(mt + 4) * 128];
            __builtin_amdgcn_s_setprio(1);
#pragma unroll
            for (int mt = 0; mt < 4; mt++)
                acc[mt + 4][0] = __builtin_amdgcn_mfma_f32_16x16x32_bf16(afb[mt], w00, acc[mt + 4][0], 0, 0, 0);
#pragma unroll
            for (int mt = 0; mt < 4; mt++)
                acc[mt + 4][1] = __builtin_amdgcn_mfma_f32_16x16x32_bf16(afb[mt], w01, acc[mt + 4][1], 0, 0, 0);
            __builtin_amdgcn_s_setprio(0);
            w00 = w10; w01 = w11; w10 = n0; w11 = n1;
        }

        if (it < 2) {
            __syncthreads();   // B3: all t reads complete before region overwrite
            // h'^T = relu(acc + bias) -> own HT rows wid*32..+32 (then straight into
            // next phase-T, no barrier: same wave owns read & write)
#pragma unroll
            for (int nt = 0; nt < 2; nt++) {
                int dp = wid * 32 + nt * 16 + l16;
                float bv = bl[dp];
#pragma unroll
                for (int mt = 0; mt < 8; mt++) {
                    int c = mt * 2 + (q >> 1);
                    int off = ((c ^ (dp & 15)) << 3) + (q & 1) * 4;
                    bf16x4 pk;
#pragma unroll
                    for (int r = 0; r < 4; r++) pk[r] = (bf16)fmaxf(acc[mt][nt][r] + bv, 0.f);
                    *(bf16x4*)&HT[dp * 128 + off] = pk;
                }
            }
        } else {
            // fused mean over all 128 n rows; write graph_repr direct to global and
            // logit partials to lpF (overlays AhatP: all AhatP reads ended before B2)
            float* lpF = (float*)(pool + 131072);
#pragma unroll
            for (int nt = 0; nt < 2; nt++) {
                int dp = wid * 32 + nt * 16 + l16;
                float bv = bl[dp];
                float s = 0.f;
#pragma unroll
                for (int mt = 0; mt < 8; mt++)
#pragma unroll
                    for (int r = 0; r < 4; r++)
                        s += fmaxf(acc[mt][nt][r] + bv, 0.f);
                s += __shfl_down(s, 32);
                s += __shfl_down(s, 16);
                if (lane < 16) {
                    float g = s * (1.f / 128.f);
                    out[256 + (size_t)b * 512 + dp] = g;
                    lpF[dp] = g * W_out[dp];
                }
            }
        }
    }
    __syncthreads();

    // ---------------- finalize: logit (wave-0 shuffle reduce over lpF[512])
    if (wid == 0) {
        float* lpF = (float*)(pool + 131072);
        float s = 0.f;
#pragma unroll
        for (int k = 0; k < 8; k++) s += lpF[lane + k * 64];
        s += __shfl_down(s, 32);
        s += __shfl_down(s, 16);
        s += __shfl_down(s, 8);
        s += __shfl_down(s, 4);
        s += __shfl_down(s, 2);
        s += __shfl_down(s, 1);
        if (lane == 0) out[b] = s + b_out[0];
    }
}

// ---------------------------------------------------------------- launch
extern "C" void kernel_launch(void* const* d_in, const int* in_sizes, int n_in,
                              void* d_out, int out_size, void* d_ws, size_t ws_size,
                              hipStream_t stream) {
    const float* adj      = (const float*)d_in[0];
    // d_in[1] = hidden (unused by forward)
    const float* node     = (const float*)d_in[2];
    const float* W_embed  = (const float*)d_in[3];
    const float* b_embed  = (const float*)d_in[4];
    const float* W_layers = (const float*)d_in[5];
    const float* b_layers = (const float*)d_in[6];
    const float* W_out    = (const float*)d_in[7];
    const float* b_out    = (const float*)d_in[8];
    float* out = (float*)d_out;

    char* ws = (char*)d_ws;
    bf16* PWe = (bf16*)(ws);              //     65,536 B : packed W_embed frags
    bf16* PWl = (bf16*)(ws + 65536);      //  1,572,864 B : packed W_layers frags (end 1.6 MB)

    k_pack<<<dim3(32, 4), 256, 0, stream>>>(W_embed, W_layers, PWe, PWl);
    k_mega<<<256, 1024, 0, stream>>>(adj, node, PWe, b_embed, PWl, b_layers,
                                     W_out, b_out, out);
}

// Round 9
// 229.197 us; speedup vs baseline: 1.0655x; 1.0655x over previous
//
#include <hip/hip_runtime.h>
#include <hip/hip_bf16.h>

// Problem constants: B=256, N=128, EB=5, NA=64, DIM=512, NIT=3
// out = [logit (256 f32), graph_repr (256*512 f32)]

typedef __bf16 bf16;
typedef __bf16 bf16x4 __attribute__((ext_vector_type(4)));
typedef __bf16 bf16x8 __attribute__((ext_vector_type(8)));
typedef float floatx4 __attribute__((ext_vector_type(4)));

// LDS pool = 160 KB:
//   [0, 131072): 16 wave-private 8 KB regions, time-multiplexed:
//     as HT: h^T rows d = w*32..w*32+31 live in region w (row stride 128 n,
//            16B-chunk XOR swizzle: phys chunk = c ^ (d&15))
//     as T : region w holds t[all 128 n][d = w*32..+32] as [4 dq][128 n][8 d]
//            elem = w*4096 + dq*1024 + n*8 + (d&7)
//   [131072, 163840): AhatP = packed Ahat B-frags (32 KB), written directly by the
//     prologue. frag (ntG 0..7, kk 0..3), chunk swizzle phys = mq*16 + (l16 ^ 2*mq).
//     (dead after it=2 phase-T; lpF[512] overlays here for the epilogue)
//
// Ownership invariant: wave w's phase-T reads ONLY region w (+AhatP) and writes
// ONLY region w; h'-write writes ONLY region w; embed writes ONLY region w.
// => no barrier h'-write -> phase-T -> t-write.
// Phase-W is LOCKSTEP dc=0..15 for all waves (R8 ERRATum: staggered per-wave dc
// order thrashes L3 retention of the L3-resident working set, +80 MB HBM, +16 us).

// ---------------------------------------------------------------- pack W into MFMA B-fragment order
// src f32 [K][512] -> dst bf16: dst[((td*(K/32)+tk)*64 + lane)*8 + j]
//   = src[tk*32 + (lane>>4)*8 + j][td*16 + (lane&15)]
// element address = td*(K/32)*512 + tk*512 + lane*8 + j   (per-td stride 8192 when K=512)
// grid: (td=32, z=4): z<3 -> W_layers[z] (K=512); z==3 -> W_embed (K=64)
__global__ __launch_bounds__(256) void k_pack(const float* __restrict__ We,
                                              const float* __restrict__ Wl,
                                              bf16* __restrict__ PWe,
                                              bf16* __restrict__ PWl) {
    __shared__ float S[512][17];
    int z = blockIdx.y, td = blockIdx.x;
    const float* src; bf16* dst; int K;
    if (z < 3) { src = Wl + (size_t)z * 262144; dst = PWl + (size_t)z * 262144; K = 512; }
    else       { src = We;                      dst = PWe;                      K = 64; }
    int tid = threadIdx.x;
    int x = tid & 15, y = tid >> 4;
    for (int kb = 0; kb < K; kb += 16) {
        int k = kb + y;
        S[k][x] = src[(size_t)k * 512 + td * 16 + x];
    }
    __syncthreads();
    int lane = tid & 63, w = tid >> 6, q = lane >> 4, l16 = lane & 15;
    int KT = K >> 5;
    for (int tk = w; tk < KT; tk += 4) {
        bf16x8 v;
#pragma unroll
        for (int j = 0; j < 8; j++) v[j] = (bf16)S[tk * 32 + q * 8 + j][l16];
        *(bf16x8*)&dst[(size_t)((td * KT + tk) * 64 + lane) * 8] = v;
    }
}

// ---------------------------------------------------------------- fused WLS forward
// 1024 threads (16 waves, 4/SIMD -> unified reg cap 128/wave). One block per batch.
__global__ __launch_bounds__(1024, 4) void k_mega(
    const float* __restrict__ adj,     // [256][128][128][5] f32
    const float* __restrict__ nodef,   // [256][128][64] f32
    const bf16* __restrict__ PWe,      // packed W_embed frags
    const float* __restrict__ b_embed, // [512]
    const bf16* __restrict__ PWl,      // packed W_layers frags [3][...]
    const float* __restrict__ b_layers,// [3][512]
    const float* __restrict__ W_out,   // [512]
    const float* __restrict__ b_out,   // [1]
    float* __restrict__ out)           // [256 logit][256*512 graph_repr]
{
    __shared__ __align__(16) char pool[163840];   // full 160 KB
    bf16* HT = (bf16*)pool;
    bf16* AhatP = (bf16*)(pool + 131072);

    const int b = blockIdx.x;
    const int tid = threadIdx.x;
    const int lane = tid & 63, wid = tid >> 6;     // 16 waves
    const int q = lane >> 4, l16 = lane & 15;

    // ---------------- prologue: Ahat = sum_e adj[...,1:] + I, scattered into AhatP frags
    {
        const float4* srcb = (const float4*)(adj + (size_t)b * 81920);
#pragma unroll
        for (int p = 0; p < 4; p++) {
            int t = p * 1024 + tid;                // 4-element group id, 0..4095
            const float4* ptr = srcb + (size_t)t * 5;
            float4 v0 = ptr[0], v1 = ptr[1], v2 = ptr[2], v3 = ptr[3], v4 = ptr[4];
            float s0 = v0.y + v0.z + v0.w + v1.x;
            float s1 = v1.z + v1.w + v2.x + v2.y;
            float s2 = v2.w + v3.x + v3.y + v3.z;
            float s3 = v4.x + v4.y + v4.z + v4.w;
            int n = t >> 5, m0 = (t & 31) * 4;
            bf16x4 o;
            o[0] = (bf16)(s0 + ((n == m0 + 0) ? 1.f : 0.f));
            o[1] = (bf16)(s1 + ((n == m0 + 1) ? 1.f : 0.f));
            o[2] = (bf16)(s2 + ((n == m0 + 2) ? 1.f : 0.f));
            o[3] = (bf16)(s3 + ((n == m0 + 3) ? 1.f : 0.f));
            int ntG = n >> 4, l16n = n & 15;
            int kk = m0 >> 5, mq = (m0 & 31) >> 3, half = (m0 >> 2) & 1;
            int cphys = mq * 16 + (l16n ^ (mq * 2));
            *(bf16x4*)&AhatP[(size_t)(((ntG * 4 + kk) * 64 + cphys) * 8 + half * 4)] = o;
        }
    }
    // NO barrier: embed touches only HT-own-rows/global; AhatP first read after B1.

    // ---------------- embed: HT rows wid*32..+32 = (node @ W_embed + b)^T, self-owned
    {
        const float* Ab = nodef + (size_t)b * 8192;
        floatx4 accE[8][2] = {};
#pragma unroll
        for (int kk = 0; kk < 2; kk++) {
            bf16x8 bfr[2];
#pragma unroll
            for (int nt = 0; nt < 2; nt++)
                bfr[nt] = *(const bf16x8*)&PWe[(size_t)(((wid * 2 + nt) * 2 + kk) * 64 + lane) * 8];
#pragma unroll
            for (int half = 0; half < 2; half++) {
                bf16x8 af[4];
#pragma unroll
                for (int mt = 0; mt < 4; mt++) {
                    const float* srcp = Ab + (size_t)((half * 4 + mt) * 16 + l16) * 64 + kk * 32 + q * 8;
                    float4 x = *(const float4*)srcp;
                    float4 y = *(const float4*)(srcp + 4);
                    bf16x8 v;
                    v[0] = (bf16)x.x; v[1] = (bf16)x.y; v[2] = (bf16)x.z; v[3] = (bf16)x.w;
                    v[4] = (bf16)y.x; v[5] = (bf16)y.y; v[6] = (bf16)y.z; v[7] = (bf16)y.w;
                    af[mt] = v;
                }
#pragma unroll
                for (int mt = 0; mt < 4; mt++)
#pragma unroll
                    for (int nt = 0; nt < 2; nt++)
                        accE[half * 4 + mt][nt] = __builtin_amdgcn_mfma_f32_16x16x32_bf16(af[mt], bfr[nt], accE[half * 4 + mt][nt], 0, 0, 0);
            }
        }
#pragma unroll
        for (int nt = 0; nt < 2; nt++) {
            int d = wid * 32 + nt * 16 + l16;
            float bv = b_embed[d];
#pragma unroll
            for (int mt = 0; mt < 8; mt++) {
                int c = mt * 2 + (q >> 1);                 // 16B chunk of n
                int off = ((c ^ (d & 15)) << 3) + (q & 1) * 4;
                bf16x4 pk;
#pragma unroll
                for (int r = 0; r < 4; r++) pk[r] = (bf16)(accE[mt][nt][r] + bv);
                *(bf16x4*)&HT[d * 128 + off] = pk;
            }
        }
    }
    __syncthreads();   // B1: AhatP ready (HT rows are self-owned, no sync needed for them)

    const int pc = lane ^ ((lane >> 4) * 2);       // AhatP phys chunk for this lane

    // ---------------- 3 WLS iterations (2 barriers each)
    for (int it = 0; it < 3; it++) {
        const bf16* WT = PWl + (size_t)it * 262144;
        const float* bl = b_layers + it * 512;

        // per-wave W frag base pointers: frag(td, dc) at td*8192 + dc*512 + lane*8
        const bf16* Wb0 = WT + (size_t)(wid * 2 + 0) * 8192 + lane * 8;
        const bf16* Wb1 = WT + (size_t)(wid * 2 + 1) * 8192 + lane * 8;

        // dc=0,1 W-frag prefetch: lands during phase-T (lockstep across waves)
        bf16x8 w00 = *(const bf16x8*)Wb0;
        bf16x8 w01 = *(const bf16x8*)Wb1;
        bf16x8 w10 = *(const bf16x8*)(Wb0 + 512);
        bf16x8 w11 = *(const bf16x8*)(Wb1 + 512);

        // ----- phase T: at[dt][nt] = t tile [32 d x 128 n], fully wave-private, no barriers
        floatx4 at[2][8] = {};
#pragma unroll
        for (int kk = 0; kk < 4; kk++) {
            bf16x8 afr[2];
#pragma unroll
            for (int dt = 0; dt < 2; dt++) {
                int drow = wid * 32 + dt * 16 + l16;
                int off = ((4 * kk + q) ^ (drow & 15)) << 3;
                afr[dt] = *(const bf16x8*)&HT[drow * 128 + off];
            }
#pragma unroll
            for (int g = 0; g < 2; g++) {
                bf16x8 bfr[4];
#pragma unroll
                for (int nt = 0; nt < 4; nt++)
                    bfr[nt] = *(const bf16x8*)&AhatP[(size_t)(((g * 4 + nt) * 4 + kk) * 64 + pc) * 8];
                __builtin_amdgcn_s_setprio(1);
#pragma unroll
                for (int nt = 0; nt < 4; nt++)
#pragma unroll
                    for (int dt = 0; dt < 2; dt++)
                        at[dt][g * 4 + nt] = __builtin_amdgcn_mfma_f32_16x16x32_bf16(afr[dt], bfr[nt], at[dt][g * 4 + nt], 0, 0, 0);
                __builtin_amdgcn_s_setprio(0);
            }
        }
        {
            // write t into own region w: elem = wid*4096 + dq*1024 + n*8 + (d&7)
            // C frag: col n = l16 (tile nt), row d_local = dt*16 + q*4 + r
            bf16* Treg = HT + wid * 4096;
#pragma unroll
            for (int dt = 0; dt < 2; dt++)
#pragma unroll
                for (int nt = 0; nt < 8; nt++) {
                    int n = nt * 16 + l16;
                    bf16x4 pk;
#pragma unroll
                    for (int r = 0; r < 4; r++) pk[r] = (bf16)at[dt][nt][r];
                    *(bf16x4*)&Treg[(dt * 2 + (q >> 1)) * 1024 + n * 8 + (q & 1) * 4] = pk;
                }
        }
        __syncthreads();   // B2: t complete

        // ----- phase W: acc = t @ W[it], K=512 over 16 dc lockstep, depth-2 W prefetch
        floatx4 acc[8][2] = {};   // [mt: n-tile][nt: d'-tile]
        for (int dc = 0; dc < 16; dc++) {
            int dcn = (dc + 2) & 15;   // branchless depth-2 (wraps harmlessly at the tail)
            bf16x8 n0 = *(const bf16x8*)(Wb0 + dcn * 512);
            bf16x8 n1 = *(const bf16x8*)(Wb1 + dcn * 512);
            const bf16* Tdc = HT + dc * 4096 + q * 1024 + l16 * 8;   // region dc, k-quad q
            bf16x8 afa[4];
#pragma unroll
            for (int mt = 0; mt < 4; mt++)
                afa[mt] = *(const bf16x8*)&Tdc[mt * 128];
            __builtin_amdgcn_s_setprio(1);
#pragma unroll
            for (int mt = 0; mt < 4; mt++)
                acc[mt][0] = __builtin_amdgcn_mfma_f32_16x16x32_bf16(afa[mt], w00, acc[mt][0], 0, 0, 0);
#pragma unroll
            for (int mt = 0; mt < 4; mt++)
                acc[mt][1] = __builtin_amdgcn_mfma_f32_16x16x32_bf16(afa[mt], w01, acc[mt][1], 0, 0, 0);
            __builtin_amdgcn_s_setprio(0);
            bf16x8 afb[4];
#pragma unroll
            for (int mt = 0; mt < 4; mt++)
                afb[mt] = *(const bf16x8*)&Tdc[(mt + 4) * 128];
            __builtin_amdgcn_s_setprio(1);
#pragma unroll
            for (int mt = 0; mt < 4; mt++)
                acc[mt + 4][0] = __builtin_amdgcn_mfma_f32_16x16x32_bf16(afb[mt], w00, acc[mt + 4][0], 0, 0, 0);
#pragma unroll
            for (int mt = 0; mt < 4; mt++)
                acc[mt + 4][1] = __builtin_amdgcn_mfma_f32_16x16x32_bf16(afb[mt], w01, acc[mt + 4][1], 0, 0, 0);
            __builtin_amdgcn_s_setprio(0);
            w00 = w10; w01 = w11; w10 = n0; w11 = n1;
        }

        if (it < 2) {
            __syncthreads();   // B3: all t reads complete before region overwrite
            // h'^T = relu(acc + bias) -> own HT rows wid*32..+32 (then straight into
            // next phase-T, no barrier: same wave owns read & write)
#pragma unroll
            for (int nt = 0; nt < 2; nt++) {
                int dp = wid * 32 + nt * 16 + l16;
                float bv = bl[dp];
#pragma unroll
                for (int mt = 0; mt < 8; mt++) {
                    int c = mt * 2 + (q >> 1);
                    int off = ((c ^ (dp & 15)) << 3) + (q & 1) * 4;
                    bf16x4 pk;
#pragma unroll
                    for (int r = 0; r < 4; r++) pk[r] = (bf16)fmaxf(acc[mt][nt][r] + bv, 0.f);
                    *(bf16x4*)&HT[dp * 128 + off] = pk;
                }
            }
        } else {
            // fused mean over all 128 n rows; write graph_repr direct to global and
            // logit partials to lpF (overlays AhatP: all AhatP reads ended before B2)
            float* lpF = (float*)(pool + 131072);
#pragma unroll
            for (int nt = 0; nt < 2; nt++) {
                int dp = wid * 32 + nt * 16 + l16;
                float bv = bl[dp];
                float s = 0.f;
#pragma unroll
                for (int mt = 0; mt < 8; mt++)
#pragma unroll
                    for (int r = 0; r < 4; r++)
                        s += fmaxf(acc[mt][nt][r] + bv, 0.f);
                s += __shfl_down(s, 32);
                s += __shfl_down(s, 16);
                if (lane < 16) {
                    float g = s * (1.f / 128.f);
                    out[256 + (size_t)b * 512 + dp] = g;
                    lpF[dp] = g * W_out[dp];
                }
            }
        }
    }
    __syncthreads();

    // ---------------- finalize: logit (wave-0 shuffle reduce over lpF[512])
    if (wid == 0) {
        float* lpF = (float*)(pool + 131072);
        float s = 0.f;
#pragma unroll
        for (int k = 0; k < 8; k++) s += lpF[lane + k * 64];
        s += __shfl_down(s, 32);
        s += __shfl_down(s, 16);
        s += __shfl_down(s, 8);
        s += __shfl_down(s, 4);
        s += __shfl_down(s, 2);
        s += __shfl_down(s, 1);
        if (lane == 0) out[b] = s + b_out[0];
    }
}

// ---------------------------------------------------------------- launch
extern "C" void kernel_launch(void* const* d_in, const int* in_sizes, int n_in,
                              void* d_out, int out_size, void* d_ws, size_t ws_size,
                              hipStream_t stream) {
    const float* adj      = (const float*)d_in[0];
    // d_in[1] = hidden (unused by forward)
    const float* node     = (const float*)d_in[2];
    const float* W_embed  = (const float*)d_in[3];
    const float* b_embed  = (const float*)d_in[4];
    const float* W_layers = (const float*)d_in[5];
    const float* b_layers = (const float*)d_in[6];
    const float* W_out    = (const float*)d_in[7];
    const float* b_out    = (const float*)d_in[8];
    float* out = (float*)d_out;

    char* ws = (char*)d_ws;
    bf16* PWe = (bf16*)(ws);              //     65,536 B : packed W_embed frags
    bf16* PWl = (bf16*)(ws + 65536);      //  1,572,864 B : packed W_layers frags (end 1.6 MB)

    k_pack<<<dim3(32, 4), 256, 0, stream>>>(W_embed, W_layers, PWe, PWl);
    k_mega<<<256, 1024, 0, stream>>>(adj, node, PWe, b_embed, PWl, b_layers,
                                     W_out, b_out, out);
}